// Round 3
// baseline (172.075 us; speedup 1.0000x reference)
//
#include <hip/hip_runtime.h>

#define N_SAMP 32
#define D_FEAT 32768
#define TVAL 100.0f
#define SIN_C 15.91549430918953f   // 100 / (2*pi): v_sin_f32 takes revolutions
#define CHUNKS 32
#define CHUNK_F 1024               // D_FEAT / CHUNKS
#define NJOBS 136                  // 36 xx + 36 yy + 64 xy
#define NBLK (NJOBS * CHUNKS)      // 4352 = 17 * 256 CUs

// ---------------------------------------------------------------------------
// Kernel 1: AvgPool2d(4,4) on (32,128,64,64) -> [32, 32768] row-major.
// MLP-first design: each thread emits 4 pooled outputs along hp, loading 16
// INDEPENDENT float4s (16 consecutive input rows) before any reduction, so
// 16 loads/thread are in flight (prev version: VGPR=12 -> ~2 in flight,
// latency-bound at 22% HBM).
// ---------------------------------------------------------------------------
__global__ __launch_bounds__(256) void pool_kernel(const float* __restrict__ xa,
                                                   const float* __restrict__ xb,
                                                   float* __restrict__ fa,
                                                   float* __restrict__ fb) {
    const float* in = blockIdx.y ? xb : xa;
    float* out = blockIdx.y ? fb : fa;
    int g  = blockIdx.x * 256 + threadIdx.x;   // 0..262143 (1M outputs / 4)
    int wp = g & 15;
    int hq = (g >> 4) & 3;                     // hp quadrant (4 hp values each)
    int c  = (g >> 6) & 127;
    int b  = g >> 13;
    // 16 consecutive input rows hq*16 .. hq*16+15, one float4 at col wp*4
    const float* p = in + (size_t)(b * 128 + c) * 4096 + hq * 1024 + wp * 4;
    float4 v[16];
#pragma unroll
    for (int k = 0; k < 16; ++k) v[k] = *(const float4*)(p + k * 64);

    float* o = out + (size_t)b * 32768 + c * 256 + hq * 64 + wp;
#pragma unroll
    for (int r = 0; r < 4; ++r) {              // output hp = hq*4 + r
        float s = 0.f;
#pragma unroll
        for (int row = 0; row < 4; ++row) {
            float4 t = v[r * 4 + row];
            s += (t.x + t.y) + (t.z + t.w);
        }
        o[r * 16] = s * 0.0625f;               // lanes 0..15 -> 64B contiguous
    }
}

// sinc term: d==0 -> T else sin(d*T)/d. v_cndmask is a bitwise select, so the
// NaN from 0*inf on the d==0 lane never propagates.
__device__ __forceinline__ float kf(float a, float b) {
    float d = a - b;
    float s = __builtin_amdgcn_sinf(d * SIN_C);   // == sin(d*100)
    float q = s * __builtin_amdgcn_rcpf(d);
    return (d == 0.0f) ? TVAL : q;
}

// ---------------------------------------------------------------------------
// Kernel 2: MMD partial sums, symmetry-reduced.
//   job < 36        : xx upper-tri tile (ti<=tj), weight = (ti==tj) ? 1 : 2
//   36 <= job < 72  : yy likewise
//   job >= 72       : xy full 8x8 tiles, weight = -2
// ---------------------------------------------------------------------------
__global__ __launch_bounds__(256) void mmd_kernel(const float* __restrict__ fa,
                                                  const float* __restrict__ fb,
                                                  float* __restrict__ partials) {
    int blk   = blockIdx.x;
    int chunk = blk & (CHUNKS - 1);
    int job   = blk >> 5;

    const float* A;
    const float* B;
    float w;
    if (job < 72) {
        int q = (job >= 36) ? job - 36 : job;
        const float* base = (job >= 36) ? fb : fa;
        int ti = 0, u = q;
        while (u >= 8 - ti) { u -= 8 - ti; ++ti; }
        int tj = ti + u;
        A = base + (size_t)(ti * 4) * D_FEAT;
        B = base + (size_t)(tj * 4) * D_FEAT;
        w = (ti == tj) ? 1.0f : 2.0f;
    } else {
        int q = job - 72;
        A = fa + (size_t)((q >> 3) * 4) * D_FEAT;
        B = fb + (size_t)((q & 7) * 4) * D_FEAT;
        w = -2.0f;
    }

    int f = chunk * CHUNK_F + threadIdx.x * 4;
    float4 av[4], bv[4];
#pragma unroll
    for (int ii = 0; ii < 4; ++ii) av[ii] = *(const float4*)(A + (size_t)ii * D_FEAT + f);
#pragma unroll
    for (int jj = 0; jj < 4; ++jj) bv[jj] = *(const float4*)(B + (size_t)jj * D_FEAT + f);

    float acc[4] = {0.f, 0.f, 0.f, 0.f};
#pragma unroll
    for (int ii = 0; ii < 4; ++ii) {
#pragma unroll
        for (int jj = 0; jj < 4; ++jj) {
            acc[jj] += kf(av[ii].x, bv[jj].x) + kf(av[ii].y, bv[jj].y)
                     + kf(av[ii].z, bv[jj].z) + kf(av[ii].w, bv[jj].w);
        }
    }
    float v = ((acc[0] + acc[1]) + (acc[2] + acc[3])) * w;

#pragma unroll
    for (int m = 1; m < 64; m <<= 1) v += __shfl_xor(v, m, 64);

    __shared__ float red[4];
    int lane = threadIdx.x & 63;
    int wave = threadIdx.x >> 6;
    if (lane == 0) red[wave] = v;
    __syncthreads();
    if (threadIdx.x == 0)
        partials[blk] = (red[0] + red[1]) + (red[2] + red[3]);
}

// ---------------------------------------------------------------------------
// Kernel 3: finalize — sum 4352 weighted partials, / (32*32*32768).
// ---------------------------------------------------------------------------
__global__ __launch_bounds__(256) void fin_kernel(const float* __restrict__ partials,
                                                  float* __restrict__ out) {
    double s = 0.0;
    for (int p = threadIdx.x; p < NBLK; p += 256) s += (double)partials[p];
    __shared__ double sh[256];
    sh[threadIdx.x] = s;
    __syncthreads();
    for (int m = 128; m > 0; m >>= 1) {
        if (threadIdx.x < m) sh[threadIdx.x] += sh[threadIdx.x + m];
        __syncthreads();
    }
    if (threadIdx.x == 0) out[0] = (float)(sh[0] / 33554432.0);
}

extern "C" void kernel_launch(void* const* d_in, const int* in_sizes, int n_in,
                              void* d_out, int out_size, void* d_ws, size_t ws_size,
                              hipStream_t stream) {
    const float* xa = (const float*)d_in[0];
    const float* xb = (const float*)d_in[1];
    float* fa = (float*)d_ws;
    float* fb = fa + (size_t)N_SAMP * D_FEAT;
    float* partials = fb + (size_t)N_SAMP * D_FEAT;
    float* out = (float*)d_out;

    dim3 pg(1024, 2);
    pool_kernel<<<pg, 256, 0, stream>>>(xa, xb, fa, fb);
    mmd_kernel<<<NBLK, 256, 0, stream>>>(fa, fb, partials);
    fin_kernel<<<1, 256, 0, stream>>>(partials, out);
}

// Round 4
// 166.748 us; speedup vs baseline: 1.0319x; 1.0319x over previous
//
#include <hip/hip_runtime.h>

#define N_SAMP 32
#define D_FEAT 32768
#define TVAL 100.0f
#define SIN_C 15.91549430918953f   // 100 / (2*pi): v_sin_f32 takes revolutions
#define CHUNKS 32
#define CHUNK_F 1024               // D_FEAT / CHUNKS
#define NJOBS 136                  // 36 xx + 36 yy + 64 xy
#define NBLK (NJOBS * CHUNKS)      // 4352 = 17 * 256 CUs

// ---------------------------------------------------------------------------
// Kernel 1: AvgPool2d(4,4) on (32,128,64,64) -> [32, 32768].
// Wave-linear streaming: one wave = 64 consecutive float4 = 1KB contiguous =
// 4 input rows = exactly one pooled row. Per thread: 1 load + 3 adds; h-pool
// via __shfl_xor(16|32); lanes 0-15 store 64B contiguous. This matches the
// 6.3 TB/s copy pattern (1 segment per load instr); prior versions issued 4
// disjoint 256B segments per instr and capped at ~3.2 TB/s effective.
// ---------------------------------------------------------------------------
__global__ __launch_bounds__(256) void pool_kernel(const float* __restrict__ xa,
                                                   const float* __restrict__ xb,
                                                   float* __restrict__ fa,
                                                   float* __restrict__ fb) {
    const float4* in4 = (const float4*)(blockIdx.y ? xb : xa);
    float* out = blockIdx.y ? fb : fa;
    int lane = threadIdx.x & 63;
#pragma unroll
    for (int it = 0; it < 8; ++it) {
        // float4 index, linear across the entire grid at each iteration
        size_t f = ((size_t)it * 2048 + blockIdx.x) * 256 + threadIdx.x;
        float4 v = in4[f];
        float s = (v.x + v.y) + (v.z + v.w);   // w-pool: this lane's 4 cols
        s += __shfl_xor(s, 16, 64);            // h-pool: rows hr^1? no: hr in lane>>4
        s += __shfl_xor(s, 32, 64);            // sum over the 4 rows of the group
        if (lane < 16) {
            // f>>6 = pooled-row index (b*128+c)*16+hp; f&15 = wp
            out[((f >> 6) << 4) + (f & 15)] = s * 0.0625f;
        }
    }
}

// sinc term: d==0 -> T else sin(d*T)/d. v_cndmask is a bitwise select, so the
// NaN from 0*inf on the d==0 lane never propagates.
__device__ __forceinline__ float kf(float a, float b) {
    float d = a - b;
    float s = __builtin_amdgcn_sinf(d * SIN_C);   // == sin(d*100)
    float q = s * __builtin_amdgcn_rcpf(d);
    return (d == 0.0f) ? TVAL : q;
}

// ---------------------------------------------------------------------------
// Kernel 2: MMD partial sums, symmetry-reduced.
//   job < 36        : xx upper-tri tile (ti<=tj), weight = (ti==tj) ? 1 : 2
//   36 <= job < 72  : yy likewise
//   job >= 72       : xy full 8x8 tiles, weight = -2
// ---------------------------------------------------------------------------
__global__ __launch_bounds__(256) void mmd_kernel(const float* __restrict__ fa,
                                                  const float* __restrict__ fb,
                                                  float* __restrict__ partials) {
    int blk   = blockIdx.x;
    int chunk = blk & (CHUNKS - 1);
    int job   = blk >> 5;

    const float* A;
    const float* B;
    float w;
    if (job < 72) {
        int q = (job >= 36) ? job - 36 : job;
        const float* base = (job >= 36) ? fb : fa;
        int ti = 0, u = q;
        while (u >= 8 - ti) { u -= 8 - ti; ++ti; }
        int tj = ti + u;
        A = base + (size_t)(ti * 4) * D_FEAT;
        B = base + (size_t)(tj * 4) * D_FEAT;
        w = (ti == tj) ? 1.0f : 2.0f;
    } else {
        int q = job - 72;
        A = fa + (size_t)((q >> 3) * 4) * D_FEAT;
        B = fb + (size_t)((q & 7) * 4) * D_FEAT;
        w = -2.0f;
    }

    int f = chunk * CHUNK_F + threadIdx.x * 4;
    float4 av[4], bv[4];
#pragma unroll
    for (int ii = 0; ii < 4; ++ii) av[ii] = *(const float4*)(A + (size_t)ii * D_FEAT + f);
#pragma unroll
    for (int jj = 0; jj < 4; ++jj) bv[jj] = *(const float4*)(B + (size_t)jj * D_FEAT + f);

    float acc[4] = {0.f, 0.f, 0.f, 0.f};
#pragma unroll
    for (int ii = 0; ii < 4; ++ii) {
#pragma unroll
        for (int jj = 0; jj < 4; ++jj) {
            acc[jj] += kf(av[ii].x, bv[jj].x) + kf(av[ii].y, bv[jj].y)
                     + kf(av[ii].z, bv[jj].z) + kf(av[ii].w, bv[jj].w);
        }
    }
    float v = ((acc[0] + acc[1]) + (acc[2] + acc[3])) * w;

#pragma unroll
    for (int m = 1; m < 64; m <<= 1) v += __shfl_xor(v, m, 64);

    __shared__ float red[4];
    int lane = threadIdx.x & 63;
    int wave = threadIdx.x >> 6;
    if (lane == 0) red[wave] = v;
    __syncthreads();
    if (threadIdx.x == 0)
        partials[blk] = (red[0] + red[1]) + (red[2] + red[3]);
}

// ---------------------------------------------------------------------------
// Kernel 3: finalize — sum 4352 weighted partials, / (32*32*32768).
// ---------------------------------------------------------------------------
__global__ __launch_bounds__(256) void fin_kernel(const float* __restrict__ partials,
                                                  float* __restrict__ out) {
    double s = 0.0;
    for (int p = threadIdx.x; p < NBLK; p += 256) s += (double)partials[p];
    __shared__ double sh[256];
    sh[threadIdx.x] = s;
    __syncthreads();
    for (int m = 128; m > 0; m >>= 1) {
        if (threadIdx.x < m) sh[threadIdx.x] += sh[threadIdx.x + m];
        __syncthreads();
    }
    if (threadIdx.x == 0) out[0] = (float)(sh[0] / 33554432.0);
}

extern "C" void kernel_launch(void* const* d_in, const int* in_sizes, int n_in,
                              void* d_out, int out_size, void* d_ws, size_t ws_size,
                              hipStream_t stream) {
    const float* xa = (const float*)d_in[0];
    const float* xb = (const float*)d_in[1];
    float* fa = (float*)d_ws;
    float* fb = fa + (size_t)N_SAMP * D_FEAT;
    float* partials = fb + (size_t)N_SAMP * D_FEAT;
    float* out = (float*)d_out;

    dim3 pg(2048, 2);
    pool_kernel<<<pg, 256, 0, stream>>>(xa, xb, fa, fb);
    mmd_kernel<<<NBLK, 256, 0, stream>>>(fa, fb, partials);
    fin_kernel<<<1, 256, 0, stream>>>(partials, out);
}

// Round 5
// 166.619 us; speedup vs baseline: 1.0327x; 1.0008x over previous
//
#include <hip/hip_runtime.h>

#define N_SAMP 32
#define D_FEAT 32768
#define TVAL 100.0f
#define SIN_C 15.91549430918953f   // 100 / (2*pi): v_sin_f32 takes revolutions
#define CHUNKS 32
#define CHUNK_F 1024               // D_FEAT / CHUNKS
#define NJOBS 136                  // 36 xx + 36 yy + 64 xy
#define NBLK (NJOBS * CHUNKS)      // 4352 = 17 * 256 CUs
#define HALF_F4 2097152            // 4.19M float4 per tensor / 2

// ---------------------------------------------------------------------------
// Kernel 1: AvgPool2d(4,4) on (32,128,64,64) -> [32, 32768].
// m13-copy-shaped: NO loop. Each thread: 2 independent float4 loads from
// far-apart halves (both live -> 2 loads in flight), w-pool in-register,
// h-pool via __shfl_xor(16|32) (one wave = 4 consecutive input rows = one
// pool group), lanes 0-15 store 64B contiguous. Max TLP: every resident wave
// has its loads issued immediately, retires, and frees the slot for a fresh
// wave with fresh loads — matches the 6.29 TB/s copy pattern's concurrency
// shape (prior loop versions: 1 outstanding load/wave for whole lifetime,
// capped at 1.8 TB/s HBM / 3.3 TB/s delivered).
// ---------------------------------------------------------------------------
__global__ __launch_bounds__(256) void pool_kernel(const float* __restrict__ xa,
                                                   const float* __restrict__ xb,
                                                   float* __restrict__ fa,
                                                   float* __restrict__ fb) {
    const float4* in4 = (const float4*)(blockIdx.y ? xb : xa);
    float* out = blockIdx.y ? fb : fa;
    size_t f0 = (size_t)blockIdx.x * 256 + threadIdx.x;  // first half window
    size_t f1 = f0 + HALF_F4;                            // second half window
    float4 v0 = in4[f0];
    float4 v1 = in4[f1];
    int lane = threadIdx.x & 63;

    float s0 = (v0.x + v0.y) + (v0.z + v0.w);
    float s1 = (v1.x + v1.y) + (v1.z + v1.w);
    s0 += __shfl_xor(s0, 16, 64);
    s1 += __shfl_xor(s1, 16, 64);
    s0 += __shfl_xor(s0, 32, 64);
    s1 += __shfl_xor(s1, 32, 64);
    if (lane < 16) {
        // f>>6 = pool-group index (b*128+c)*16+hp ; f&15 = wp
        out[((f0 >> 6) << 4) + (f0 & 15)] = s0 * 0.0625f;
        out[((f1 >> 6) << 4) + (f1 & 15)] = s1 * 0.0625f;
    }
}

// sinc term: d==0 -> T else sin(d*T)/d. v_cndmask is a bitwise select, so the
// NaN from 0*inf on the d==0 lane never propagates.
__device__ __forceinline__ float kf(float a, float b) {
    float d = a - b;
    float s = __builtin_amdgcn_sinf(d * SIN_C);   // == sin(d*100)
    float q = s * __builtin_amdgcn_rcpf(d);
    return (d == 0.0f) ? TVAL : q;
}

// ---------------------------------------------------------------------------
// Kernel 2: MMD partial sums, symmetry-reduced.
//   job < 36        : xx upper-tri tile (ti<=tj), weight = (ti==tj) ? 1 : 2
//   36 <= job < 72  : yy likewise
//   job >= 72       : xy full 8x8 tiles, weight = -2
// ---------------------------------------------------------------------------
__global__ __launch_bounds__(256) void mmd_kernel(const float* __restrict__ fa,
                                                  const float* __restrict__ fb,
                                                  float* __restrict__ partials) {
    int blk   = blockIdx.x;
    int chunk = blk & (CHUNKS - 1);
    int job   = blk >> 5;

    const float* A;
    const float* B;
    float w;
    if (job < 72) {
        int q = (job >= 36) ? job - 36 : job;
        const float* base = (job >= 36) ? fb : fa;
        int ti = 0, u = q;
        while (u >= 8 - ti) { u -= 8 - ti; ++ti; }
        int tj = ti + u;
        A = base + (size_t)(ti * 4) * D_FEAT;
        B = base + (size_t)(tj * 4) * D_FEAT;
        w = (ti == tj) ? 1.0f : 2.0f;
    } else {
        int q = job - 72;
        A = fa + (size_t)((q >> 3) * 4) * D_FEAT;
        B = fb + (size_t)((q & 7) * 4) * D_FEAT;
        w = -2.0f;
    }

    int f = chunk * CHUNK_F + threadIdx.x * 4;
    float4 av[4], bv[4];
#pragma unroll
    for (int ii = 0; ii < 4; ++ii) av[ii] = *(const float4*)(A + (size_t)ii * D_FEAT + f);
#pragma unroll
    for (int jj = 0; jj < 4; ++jj) bv[jj] = *(const float4*)(B + (size_t)jj * D_FEAT + f);

    float acc[4] = {0.f, 0.f, 0.f, 0.f};
#pragma unroll
    for (int ii = 0; ii < 4; ++ii) {
#pragma unroll
        for (int jj = 0; jj < 4; ++jj) {
            acc[jj] += kf(av[ii].x, bv[jj].x) + kf(av[ii].y, bv[jj].y)
                     + kf(av[ii].z, bv[jj].z) + kf(av[ii].w, bv[jj].w);
        }
    }
    float v = ((acc[0] + acc[1]) + (acc[2] + acc[3])) * w;

#pragma unroll
    for (int m = 1; m < 64; m <<= 1) v += __shfl_xor(v, m, 64);

    __shared__ float red[4];
    int lane = threadIdx.x & 63;
    int wave = threadIdx.x >> 6;
    if (lane == 0) red[wave] = v;
    __syncthreads();
    if (threadIdx.x == 0)
        partials[blk] = (red[0] + red[1]) + (red[2] + red[3]);
}

// ---------------------------------------------------------------------------
// Kernel 3: finalize — sum 4352 weighted partials, / (32*32*32768).
// ---------------------------------------------------------------------------
__global__ __launch_bounds__(256) void fin_kernel(const float* __restrict__ partials,
                                                  float* __restrict__ out) {
    double s = 0.0;
    for (int p = threadIdx.x; p < NBLK; p += 256) s += (double)partials[p];
    __shared__ double sh[256];
    sh[threadIdx.x] = s;
    __syncthreads();
    for (int m = 128; m > 0; m >>= 1) {
        if (threadIdx.x < m) sh[threadIdx.x] += sh[threadIdx.x + m];
        __syncthreads();
    }
    if (threadIdx.x == 0) out[0] = (float)(sh[0] / 33554432.0);
}

extern "C" void kernel_launch(void* const* d_in, const int* in_sizes, int n_in,
                              void* d_out, int out_size, void* d_ws, size_t ws_size,
                              hipStream_t stream) {
    const float* xa = (const float*)d_in[0];
    const float* xb = (const float*)d_in[1];
    float* fa = (float*)d_ws;
    float* fb = fa + (size_t)N_SAMP * D_FEAT;
    float* partials = fb + (size_t)N_SAMP * D_FEAT;
    float* out = (float*)d_out;

    dim3 pg(8192, 2);   // 8192*256 threads * 2 f4 = 4.19M float4 per tensor
    pool_kernel<<<pg, 256, 0, stream>>>(xa, xb, fa, fb);
    mmd_kernel<<<NBLK, 256, 0, stream>>>(fa, fb, partials);
    fin_kernel<<<1, 256, 0, stream>>>(partials, out);
}